// Round 13
// baseline (153.511 us; speedup 1.0000x reference)
//
#include <hip/hip_runtime.h>

#define BD 8
#define SD 64
#define CD 3
#define HD 224
#define WD 224
#define ED 128
#define PD 16
#define HWD (HD*WD)
#define KD (CD*PD*PD)   /* 768 */
#define PRT 8           /* partitions per (b,c) for the hierarchical scatter */
#define CHK (HWD/PRT)   /* 6272 pixels per partition */

// All buffers fp32 (confirmed R6+ passes). Scratch in module globals; every
// byte is fully overwritten each call (no zero-init dispatch) and there are
// NO global atomics anywhere (R9: atomic scatter = 30MB line-grain RMW ~66us;
// R10: flat gather 64x label re-scan = 133us; R11: hierarchical = win).
// R12 negatives: PIX=4 weight amortization neutral (k_labels is at its fp32
// VALU issue floor, not weight-bound); dispatch-count reduction neutral.
__device__ float              g_part[BD * CD * PRT * SD * 256];  // 12.6 MB partials
__device__ int                g_labels[BD * HWD];
__device__ unsigned long long g_ppres[BD * PRT];                 // presence per (b,part)

// Kernel 1: 3x3 SAME conv -> argmax(64ch) -> labels. R10/R11-proven exact form.
__global__ __launch_bounds__(256) void k_labels(
    const float* __restrict__ img,
    const float* __restrict__ wsp,
    const float* __restrict__ bsp)
{
    const int w = blockIdx.x * 64 + threadIdx.x;
    const int h = blockIdx.y * 4 + threadIdx.y;
    const int b = blockIdx.z;
    if (w >= WD) return;

    const float* ib = img + (size_t)b * CD * HWD;
    float pix[27];
    #pragma unroll
    for (int c = 0; c < 3; ++c)
        #pragma unroll
        for (int dh = 0; dh < 3; ++dh)
            #pragma unroll
            for (int dw = 0; dw < 3; ++dw) {
                int hh = h + dh - 1, ww = w + dw - 1;
                bool ok = (hh >= 0) & (hh < HD) & (ww >= 0) & (ww < WD);
                pix[(c * 3 + dh) * 3 + dw] = ok ? ib[c * HWD + hh * WD + ww] : 0.f;
            }

    float best = -INFINITY;
    int bi = 0;
    for (int s = 0; s < SD; ++s) {
        const float* wr = wsp + s * 27;        // wave-uniform -> s_load
        float acc = bsp[s];
        #pragma unroll
        for (int j = 0; j < 27; ++j) acc = fmaf(pix[j], wr[j], acc);
        if (acc > best) { best = acc; bi = s; }   // strict > = first max (jnp.argmax)
    }
    g_labels[b * HWD + h * WD + w] = bi;
}

// Kernel 2: hierarchical scatter. Block = (partition, channel, batch); owns a
// 6272-pixel chunk, accumulates into a 64KB LDS table [lab][cell] via LDS
// atomics (<=4-way conflicts), writes its partial table exclusively (coalesced).
// Presence mask per (b,part) from in-register OR + wave shfl-OR (c==0 blocks).
__global__ __launch_bounds__(256) void k_hist(const float* __restrict__ img)
{
    const int part = blockIdx.x, c = blockIdx.y, b = blockIdx.z;
    const int tid = threadIdx.x;

    __shared__ float acc[SD * 256];            // 64 KB
    __shared__ unsigned long long pm;
    #pragma unroll
    for (int k = 0; k < 16; ++k)
        ((float4*)acc)[k * 256 + tid] = make_float4(0.f, 0.f, 0.f, 0.f);
    if (tid == 0) pm = 0ull;
    __syncthreads();

    const int start = part * CHK;
    const int*   lb = g_labels + (size_t)b * HWD;
    const float* ic = img + ((size_t)b * CD + c) * HWD;

    unsigned long long m = 0ull;
    for (int p = start + tid; p < start + CHK; p += 256) {
        const int lab = lb[p];                 // coalesced, L2-resident
        const int h = p / WD, w = p - h * WD;
        const int cell = ((h & 15) << 4) | (w & 15);
        atomicAdd(&acc[lab * 256 + cell], ic[p]);
        m |= 1ull << lab;
    }
    #pragma unroll
    for (int d = 1; d < 64; d <<= 1) m |= __shfl_xor(m, d, 64);
    if ((tid & 63) == 0) atomicOr(&pm, m);
    __syncthreads();

    float4* dst = (float4*)(g_part + (((size_t)(b * CD + c)) * PRT + part) * (SD * 256));
    #pragma unroll
    for (int k = 0; k < 16; ++k)
        dst[k * 256 + tid] = ((float4*)acc)[k * 256 + tid];
    if (c == 0 && tid == 0) g_ppres[b * PRT + part] = pm;
}

// Kernel 3: out[b,i,e] = bias[e] + (1/196)*dot(G[b,uniq(b,i),:], wp[e,:]).
// Block owns 4 consecutive i's: wp L2 traffic /4 (201->50 MB). Merge of the
// PRT partials builds 4 g-rows in 12KB LDS; per-i summation order identical
// to R12 -> bit-identical outputs. lane=k-dim coalesced wp dot + shfl reduce.
__global__ __launch_bounds__(256) void k_out(
    const float* __restrict__ wp,
    const float* __restrict__ bp,
    float* __restrict__ out)
{
    __shared__ float4 gs4[4][KD / 4];          // 4 x 192 float4 = 12 KB
    const int i0 = blockIdx.x * 4;
    const int b  = blockIdx.y;
    const int tid = threadIdx.x;
    const int lane = tid & 63;
    const int wv = tid >> 6;

    unsigned long long m = 0ull;
    #pragma unroll
    for (int p2 = 0; p2 < PRT; ++p2) m |= g_ppres[b * PRT + p2];  // uniform -> s_load
    const int npres = __popcll(m);

    int lsel[4];
    #pragma unroll
    for (int ii = 0; ii < 4; ++ii) {
        int l = 0;
        if (i0 + ii < npres) {
            unsigned long long mm = m;
            for (int t = 0; t < i0 + ii; ++t) mm &= mm - 1;
            l = __builtin_ctzll(mm);           // (i0+ii)-th smallest label
        }
        lsel[ii] = l;
    }

    // merge: 768 float4-slots = 4 rows x 192, 3 per thread
    #pragma unroll
    for (int r = 0; r < 3; ++r) {
        const int t = r * 256 + tid;
        const int ii = t / 192, k4 = t - ii * 192;
        const int c = k4 >> 6, cell4 = k4 & 63;
        const float4* src = (const float4*)g_part
            + ((size_t)(b * CD + c) * PRT) * 4096 + lsel[ii] * 64 + cell4;
        float4 s = src[0];
        #pragma unroll
        for (int p2 = 1; p2 < PRT; ++p2) {
            float4 v = src[(size_t)p2 * 4096];
            s.x += v.x; s.y += v.y; s.z += v.z; s.w += v.w;
        }
        gs4[ii][k4] = s;
    }
    __syncthreads();

    #pragma unroll 2
    for (int j = 0; j < 32; ++j) {
        const int e = wv * 32 + j;
        const float4* wr = (const float4*)(wp + (size_t)e * KD);
        const float4 a0 = wr[lane], a1 = wr[lane + 64], a2 = wr[lane + 128];  // 1KB/wave
        #pragma unroll
        for (int ii = 0; ii < 4; ++ii) {
            const float4 g0 = gs4[ii][lane], g1 = gs4[ii][lane + 64], g2 = gs4[ii][lane + 128];
            float acc = g0.x * a0.x;
            acc = fmaf(g0.y, a0.y, acc); acc = fmaf(g0.z, a0.z, acc); acc = fmaf(g0.w, a0.w, acc);
            acc = fmaf(g1.x, a1.x, acc); acc = fmaf(g1.y, a1.y, acc);
            acc = fmaf(g1.z, a1.z, acc); acc = fmaf(g1.w, a1.w, acc);
            acc = fmaf(g2.x, a2.x, acc); acc = fmaf(g2.y, a2.y, acc);
            acc = fmaf(g2.z, a2.z, acc); acc = fmaf(g2.w, a2.w, acc);
            #pragma unroll
            for (int off = 32; off; off >>= 1) acc += __shfl_xor(acc, off, 64);
            if (lane == 0)
                out[(size_t)(b * SD + i0 + ii) * ED + e] = bp[e] + acc * (1.f / 196.f);
        }
    }
}

extern "C" void kernel_launch(void* const* d_in, const int* in_sizes, int n_in,
                              void* d_out, int out_size, void* d_ws, size_t ws_size,
                              hipStream_t stream) {
    const float *img = nullptr, *wsp = nullptr, *bsp = nullptr, *wp = nullptr, *bp = nullptr;
    for (int i = 0; i < n_in; ++i) {
        switch (in_sizes[i]) {
            case BD * CD * HWD:      img = (const float*)d_in[i]; break;  // 1204224
            case SD * CD * 9:        wsp = (const float*)d_in[i]; break;  // 1728
            case SD:                 bsp = (const float*)d_in[i]; break;  // 64
            case ED * CD * PD * PD:  wp  = (const float*)d_in[i]; break;  // 98304
            case ED:                 bp  = (const float*)d_in[i]; break;  // 128
        }
    }
    float* out = (float*)d_out;

    dim3 b1(64, 4, 1), g1(4, 56, BD);
    k_labels<<<g1, b1, 0, stream>>>(img, wsp, bsp);

    dim3 g2(PRT, CD, BD);
    k_hist<<<g2, 256, 0, stream>>>(img);

    dim3 g3(SD / 4, BD, 1);
    k_out<<<g3, 256, 0, stream>>>(wp, bp, out);
}

// Round 14
// 133.972 us; speedup vs baseline: 1.1458x; 1.1458x over previous
//
#include <hip/hip_runtime.h>

#define BD 8
#define SD 64
#define CD 3
#define HD 224
#define WD 224
#define ED 128
#define PD 16
#define HWD (HD*WD)
#define KD (CD*PD*PD)   /* 768 */
#define PRT 8           /* partitions per (b,c) for the hierarchical scatter */
#define CHK (HWD/PRT)   /* 6272 pixels per partition */

// All buffers fp32 (confirmed R6+ passes). Scratch in module globals; every
// byte is fully overwritten each call (no zero-init dispatch) and there are
// NO global atomics anywhere (R9: atomic scatter = 30MB line-grain RMW ~66us;
// R10: flat gather 64x label re-scan = 133us; R11: hierarchical = win, 135.6us).
// R12 negative: PIX=4 weight amortization neutral. R13 negative: k_out 4-i
// blocks (128 total) -> occupancy collapse, 50us; grid >= 256 blocks beats
// any L2-traffic saving at this size.
__device__ float              g_part[BD * CD * PRT * SD * 256];  // 12.6 MB partials
__device__ int                g_labels[BD * HWD];
__device__ unsigned long long g_ppres[BD * PRT];                 // presence per (b,part)

// Kernel 1: 3x3 SAME conv -> argmax(64ch) -> labels. R10/R11-proven math;
// linear pixel indexing (HWD = 196*256 exactly) -> 100% active lanes
// (R11's column mapping idled 12.5% behind the w<224 guard).
__global__ __launch_bounds__(256) void k_labels(
    const float* __restrict__ img,
    const float* __restrict__ wsp,
    const float* __restrict__ bsp)
{
    const int p = blockIdx.x * 256 + threadIdx.x;
    const int b = blockIdx.y;
    const int h = p / WD;
    const int w = p - h * WD;

    const float* ib = img + (size_t)b * CD * HWD;
    float pix[27];
    #pragma unroll
    for (int c = 0; c < 3; ++c)
        #pragma unroll
        for (int dh = 0; dh < 3; ++dh)
            #pragma unroll
            for (int dw = 0; dw < 3; ++dw) {
                int hh = h + dh - 1, ww = w + dw - 1;
                bool ok = (hh >= 0) & (hh < HD) & (ww >= 0) & (ww < WD);
                pix[(c * 3 + dh) * 3 + dw] = ok ? ib[c * HWD + hh * WD + ww] : 0.f;
            }

    float best = -INFINITY;
    int bi = 0;
    for (int s = 0; s < SD; ++s) {
        const float* wr = wsp + s * 27;        // wave-uniform -> s_load
        float acc = bsp[s];
        #pragma unroll
        for (int j = 0; j < 27; ++j) acc = fmaf(pix[j], wr[j], acc);
        if (acc > best) { best = acc; bi = s; }   // strict > = first max (jnp.argmax)
    }
    g_labels[b * HWD + p] = bi;
}

// Kernel 2: hierarchical scatter. Block = (partition, channel, batch); owns a
// 6272-pixel chunk, accumulates into a 64KB LDS table [lab][cell] via LDS
// atomics (<=4-way conflicts), writes its partial table exclusively (coalesced).
// Presence mask per (b,part) from in-register OR + wave shfl-OR (c==0 blocks).
__global__ __launch_bounds__(256) void k_hist(const float* __restrict__ img)
{
    const int part = blockIdx.x, c = blockIdx.y, b = blockIdx.z;
    const int tid = threadIdx.x;

    __shared__ float acc[SD * 256];            // 64 KB
    __shared__ unsigned long long pm;
    #pragma unroll
    for (int k = 0; k < 16; ++k)
        ((float4*)acc)[k * 256 + tid] = make_float4(0.f, 0.f, 0.f, 0.f);
    if (tid == 0) pm = 0ull;
    __syncthreads();

    const int start = part * CHK;
    const int*   lb = g_labels + (size_t)b * HWD;
    const float* ic = img + ((size_t)b * CD + c) * HWD;

    unsigned long long m = 0ull;
    for (int p = start + tid; p < start + CHK; p += 256) {
        const int lab = lb[p];                 // coalesced, L2-resident
        const int h = p / WD, w = p - h * WD;
        const int cell = ((h & 15) << 4) | (w & 15);
        atomicAdd(&acc[lab * 256 + cell], ic[p]);
        m |= 1ull << lab;
    }
    #pragma unroll
    for (int d = 1; d < 64; d <<= 1) m |= __shfl_xor(m, d, 64);
    if ((tid & 63) == 0) atomicOr(&pm, m);
    __syncthreads();

    float4* dst = (float4*)(g_part + (((size_t)(b * CD + c)) * PRT + part) * (SD * 256));
    #pragma unroll
    for (int k = 0; k < 16; ++k)
        dst[k * 256 + tid] = ((float4*)acc)[k * 256 + tid];
    if (c == 0 && tid == 0) g_ppres[b * PRT + part] = pm;
}

// Kernel 3: out[b,i,e] = bias[e] + (1/196)*dot(G[b,uniq(b,i),:], wp[e,:]).
// R11-proven exact form: 512 blocks (one per (i,b)), merge of PRT partials
// folded in (192 threads build the 3KB g-row in LDS), lane=k-dim coalesced
// wp dot + shfl reduce.
__global__ __launch_bounds__(256) void k_out(
    const float* __restrict__ wp,
    const float* __restrict__ bp,
    float* __restrict__ out)
{
    __shared__ float4 gs4[KD / 4];             // 192 float4 = 3 KB
    const int i = blockIdx.x;
    const int b = blockIdx.y;
    const int tid = threadIdx.x;
    const int lane = tid & 63;
    const int wv = tid >> 6;

    unsigned long long m = 0ull;
    #pragma unroll
    for (int p2 = 0; p2 < PRT; ++p2) m |= g_ppres[b * PRT + p2];  // uniform -> s_load

    int l = 0;
    if (i < __popcll(m)) {
        unsigned long long mm = m;
        for (int t = 0; t < i; ++t) mm &= mm - 1;   // clear i lowest set bits
        l = __builtin_ctzll(mm);                    // i-th smallest label (sorted unique)
    }

    if (tid < KD / 4) {
        const int c = tid >> 6, cell4 = tid & 63;
        const float4* src = (const float4*)g_part
            + ((size_t)(b * CD + c) * PRT) * 4096 + l * 64 + cell4;
        float4 s = src[0];
        #pragma unroll
        for (int p2 = 1; p2 < PRT; ++p2) {
            float4 v = src[(size_t)p2 * 4096];
            s.x += v.x; s.y += v.y; s.z += v.z; s.w += v.w;
        }
        gs4[tid] = s;
    }
    __syncthreads();

    const float4 g0 = gs4[lane], g1 = gs4[lane + 64], g2 = gs4[lane + 128];

    #pragma unroll 4
    for (int j = 0; j < 32; ++j) {
        const int e = wv * 32 + j;
        const float4* wr = (const float4*)(wp + (size_t)e * KD);
        float4 a0 = wr[lane], a1 = wr[lane + 64], a2 = wr[lane + 128];  // coalesced 1KB/wave
        float acc = g0.x * a0.x;
        acc = fmaf(g0.y, a0.y, acc); acc = fmaf(g0.z, a0.z, acc); acc = fmaf(g0.w, a0.w, acc);
        acc = fmaf(g1.x, a1.x, acc); acc = fmaf(g1.y, a1.y, acc);
        acc = fmaf(g1.z, a1.z, acc); acc = fmaf(g1.w, a1.w, acc);
        acc = fmaf(g2.x, a2.x, acc); acc = fmaf(g2.y, a2.y, acc);
        acc = fmaf(g2.z, a2.z, acc); acc = fmaf(g2.w, a2.w, acc);
        #pragma unroll
        for (int off = 32; off; off >>= 1) acc += __shfl_xor(acc, off, 64);
        if (lane == 0)
            out[(size_t)(b * SD + i) * ED + e] = bp[e] + acc * (1.f / 196.f);
    }
}

extern "C" void kernel_launch(void* const* d_in, const int* in_sizes, int n_in,
                              void* d_out, int out_size, void* d_ws, size_t ws_size,
                              hipStream_t stream) {
    const float *img = nullptr, *wsp = nullptr, *bsp = nullptr, *wp = nullptr, *bp = nullptr;
    for (int i = 0; i < n_in; ++i) {
        switch (in_sizes[i]) {
            case BD * CD * HWD:      img = (const float*)d_in[i]; break;  // 1204224
            case SD * CD * 9:        wsp = (const float*)d_in[i]; break;  // 1728
            case SD:                 bsp = (const float*)d_in[i]; break;  // 64
            case ED * CD * PD * PD:  wp  = (const float*)d_in[i]; break;  // 98304
            case ED:                 bp  = (const float*)d_in[i]; break;  // 128
        }
    }
    float* out = (float*)d_out;

    dim3 g1(HWD / 256, BD, 1);
    k_labels<<<g1, 256, 0, stream>>>(img, wsp, bsp);

    dim3 g2(PRT, CD, BD);
    k_hist<<<g2, 256, 0, stream>>>(img);

    dim3 g3(SD, BD, 1);
    k_out<<<g3, 256, 0, stream>>>(wp, bp, out);
}